// Round 1
// baseline (2453.044 us; speedup 1.0000x reference)
//
#include <hip/hip_runtime.h>

typedef unsigned short u16;
typedef __attribute__((ext_vector_type(8))) short short8;
typedef __attribute__((ext_vector_type(4))) float f32x4;

#define BATCH 256
#define N0    512
#define N1    2048
#define NIN   4096
#define TSTEPS 60

static __device__ __forceinline__ f32x4 MFMA(short8 a, short8 b, f32x4 c) {
    return __builtin_amdgcn_mfma_f32_16x16x32_bf16(a, b, c, 0, 0, 0);
}

// x = hi + lo (both bf16, truncation split). Residual ~2^-16 relative.
static __device__ __forceinline__ void split1(float x, u16* __restrict__ hp, u16* __restrict__ lp) {
    unsigned bx = __float_as_uint(x);
    *hp = (u16)(bx >> 16);
    float lf = x - __uint_as_float(bx & 0xFFFF0000u);
    *lp = (u16)(__float_as_uint(lf) >> 16);
}

// load 8 contiguous f32 and produce hi/lo bf16x8 fragments (bit-packing, no cvt chain)
static __device__ __forceinline__ void split8(const float* __restrict__ p, short8& h, short8& l) {
    const float4 x0 = *(const float4*)p;
    const float4 x1 = *(const float4*)(p + 4);
    float xs[8] = {x0.x, x0.y, x0.z, x0.w, x1.x, x1.y, x1.z, x1.w};
    union { short8 v; unsigned u[4]; } H, L;
    #pragma unroll
    for (int j = 0; j < 4; ++j) {
        unsigned ba = __float_as_uint(xs[2*j]);
        unsigned bb = __float_as_uint(xs[2*j+1]);
        H.u[j] = (ba >> 16) | (bb & 0xFFFF0000u);
        float la = xs[2*j]   - __uint_as_float(ba & 0xFFFF0000u);
        float lb = xs[2*j+1] - __uint_as_float(bb & 0xFFFF0000u);
        L.u[j] = (__float_as_uint(la) >> 16) | (__float_as_uint(lb) & 0xFFFF0000u);
    }
    h = H.v; l = L.v;
}

static __device__ __forceinline__ float clamp01(float v) {
    return fminf(fmaxf(v, 0.0f), 1.0f);
}

// -------- prep: split weights / data / initial states into bf16 hi/lo --------
__global__ __launch_bounds__(256) void prep_kernel(
    const float* __restrict__ w0, const float* __restrict__ w1,
    const float* __restrict__ data,
    const float* __restrict__ s0, const float* __restrict__ s1,
    u16* __restrict__ w0h, u16* __restrict__ w0l,
    u16* __restrict__ w1h, u16* __restrict__ w1l,
    u16* __restrict__ dh,  u16* __restrict__ dl,
    float* __restrict__ s0f, float* __restrict__ s1f,
    u16* __restrict__ s0h, u16* __restrict__ s0l,
    u16* __restrict__ s1h, u16* __restrict__ s1l)
{
    const int tid = blockIdx.x * blockDim.x + threadIdx.x;
    const int nth = gridDim.x * blockDim.x;
    const int NW = N0 * N1;  // 1048576 == BATCH*NIN too
    for (int i = tid; i < NW; i += nth) {
        split1(w0[i],   &w0h[i], &w0l[i]);
        split1(w1[i],   &w1h[i], &w1l[i]);
        split1(data[i], &dh[i],  &dl[i]);
    }
    for (int i = tid; i < BATCH * N0; i += nth) {
        float v = s0[i]; s0f[i] = v; split1(v, &s0h[i], &s0l[i]);
    }
    for (int i = tid; i < BATCH * N1; i += nth) {
        float v = s1[i]; s1f[i] = v; split1(v, &s1h[i], &s1l[i]);
    }
}

// -------- inp1 = data @ w2^T + b2   (M=256, N=2048, K=4096) --------
// 64x64 tiles, 128 WGs, 4 waves each computing a 32x32 quadrant (2x2 frags)
__global__ __launch_bounds__(256) void inp1_kernel(
    const u16* __restrict__ dh, const u16* __restrict__ dl,
    const float* __restrict__ w2, const float* __restrict__ b2,
    float* __restrict__ inp1)
{
    const int wave = threadIdx.x >> 6, lane = threadIdx.x & 63;
    const int lrow = lane & 15, lk8 = (lane >> 4) << 3, lr4 = (lane >> 4) << 2;
    const int mbase = (int)(blockIdx.x >> 5) * 64 + (wave >> 1) * 32;
    const int nbase = (int)(blockIdx.x & 31) * 64 + (wave & 1) * 32;

    f32x4 acc[2][2] = {};
    for (int k0 = 0; k0 < NIN; k0 += 32) {
        short8 ah[2], al[2], bh[2], bl[2];
        #pragma unroll
        for (int m = 0; m < 2; ++m) {
            const size_t off = (size_t)(mbase + m * 16 + lrow) * NIN + k0 + lk8;
            ah[m] = *(const short8*)(dh + off);
            al[m] = *(const short8*)(dl + off);
        }
        #pragma unroll
        for (int n = 0; n < 2; ++n) {
            const float* pb = w2 + (size_t)(nbase + n * 16 + lrow) * NIN + k0 + lk8;
            split8(pb, bh[n], bl[n]);
        }
        #pragma unroll
        for (int m = 0; m < 2; ++m)
            #pragma unroll
            for (int n = 0; n < 2; ++n) {
                acc[m][n] = MFMA(ah[m], bh[n], acc[m][n]);
                acc[m][n] = MFMA(ah[m], bl[n], acc[m][n]);
                acc[m][n] = MFMA(al[m], bh[n], acc[m][n]);
            }
    }
    #pragma unroll
    for (int m = 0; m < 2; ++m)
        #pragma unroll
        for (int n = 0; n < 2; ++n) {
            const int col = nbase + n * 16 + lrow;
            #pragma unroll
            for (int r = 0; r < 4; ++r) {
                const int row = mbase + m * 16 + lr4 + r;
                inp1[(size_t)row * N1 + col] = acc[m][n][r] + b2[col];
            }
        }
}

// -------- one Euler step --------
// WGs 0..127  : C1 = s0 @ w0  (via w1 rows, K=512), 64x64 tiles -> s1'
// WGs 128..255: C0 = s1 @ w0^T (via w0 rows, K=2048), 32x32 tiles -> s0'
__global__ __launch_bounds__(256) void step_kernel(
    const float* __restrict__ s0f_in, const float* __restrict__ s1f_in,
    const u16* __restrict__ s0h, const u16* __restrict__ s0l,
    const u16* __restrict__ s1h, const u16* __restrict__ s1l,
    const u16* __restrict__ w0h, const u16* __restrict__ w0l,
    const u16* __restrict__ w1h, const u16* __restrict__ w1l,
    const float* __restrict__ inp1, const float* __restrict__ b0,
    float* __restrict__ s0f_out, float* __restrict__ s1f_out,
    u16* __restrict__ s0h_out, u16* __restrict__ s0l_out,
    u16* __restrict__ s1h_out, u16* __restrict__ s1l_out)
{
    const int wg = blockIdx.x;
    const int wave = threadIdx.x >> 6, lane = threadIdx.x & 63;
    const int lrow = lane & 15, lk8 = (lane >> 4) << 3, lr4 = (lane >> 4) << 2;

    if (wg < 128) {
        // s1' tile: 64 batches x 64 features, K = N0 = 512
        const int mbase = (wg >> 5) * 64 + (wave >> 1) * 32;   // batch
        const int nbase = (wg & 31) * 64 + (wave & 1) * 32;    // n1 feature
        f32x4 acc[2][2] = {};
        #pragma unroll 2
        for (int k0 = 0; k0 < N0; k0 += 32) {
            short8 ah[2], al[2], bh[2], bl[2];
            #pragma unroll
            for (int m = 0; m < 2; ++m) {
                const size_t off = (size_t)(mbase + m * 16 + lrow) * N0 + k0 + lk8;
                ah[m] = *(const short8*)(s0h + off);
                al[m] = *(const short8*)(s0l + off);
            }
            #pragma unroll
            for (int n = 0; n < 2; ++n) {
                const size_t off = (size_t)(nbase + n * 16 + lrow) * N0 + k0 + lk8;
                bh[n] = *(const short8*)(w1h + off);
                bl[n] = *(const short8*)(w1l + off);
            }
            #pragma unroll
            for (int m = 0; m < 2; ++m)
                #pragma unroll
                for (int n = 0; n < 2; ++n) {
                    acc[m][n] = MFMA(ah[m], bh[n], acc[m][n]);
                    acc[m][n] = MFMA(ah[m], bl[n], acc[m][n]);
                    acc[m][n] = MFMA(al[m], bh[n], acc[m][n]);
                }
        }
        #pragma unroll
        for (int m = 0; m < 2; ++m)
            #pragma unroll
            for (int n = 0; n < 2; ++n) {
                const int col = nbase + n * 16 + lrow;
                #pragma unroll
                for (int r = 0; r < 4; ++r) {
                    const int row = mbase + m * 16 + lr4 + r;
                    const size_t idx = (size_t)row * N1 + col;
                    float v = 0.5f * (s1f_in[idx] + inp1[idx] + acc[m][n][r]);
                    v = clamp01(v);
                    s1f_out[idx] = v;
                    split1(v, &s1h_out[idx], &s1l_out[idx]);
                }
            }
    } else {
        // s0' tile: 32 batches x 32 features, K = N1 = 2048; one 16x16 frag per wave
        const int local = wg - 128;
        const int rowbase = (local >> 4) * 32 + (wave >> 1) * 16;  // batch
        const int colbase = (local & 15) * 32 + (wave & 1) * 16;   // n0 feature
        f32x4 acc = {};
        #pragma unroll 2
        for (int k0 = 0; k0 < N1; k0 += 32) {
            const size_t aoff = (size_t)(rowbase + lrow) * N1 + k0 + lk8;
            const size_t boff = (size_t)(colbase + lrow) * N1 + k0 + lk8;
            short8 ah = *(const short8*)(s1h + aoff);
            short8 al = *(const short8*)(s1l + aoff);
            short8 bh = *(const short8*)(w0h + boff);
            short8 bl = *(const short8*)(w0l + boff);
            acc = MFMA(ah, bh, acc);
            acc = MFMA(ah, bl, acc);
            acc = MFMA(al, bh, acc);
        }
        const int col = colbase + lrow;
        const float bias = b0[col];
        #pragma unroll
        for (int r = 0; r < 4; ++r) {
            const int row = rowbase + lr4 + r;
            const size_t idx = (size_t)row * N0 + col;
            float v = 0.5f * (s0f_in[idx] + acc[r] + bias);
            v = clamp01(v);
            s0f_out[idx] = v;
            split1(v, &s0h_out[idx], &s0l_out[idx]);
        }
    }
}

extern "C" void kernel_launch(void* const* d_in, const int* in_sizes, int n_in,
                              void* d_out, int out_size, void* d_ws, size_t ws_size,
                              hipStream_t stream) {
    const float* data = (const float*)d_in[0];
    const float* s0_0 = (const float*)d_in[1];
    const float* s1_0 = (const float*)d_in[2];
    const float* w0   = (const float*)d_in[3];
    const float* b0   = (const float*)d_in[4];
    const float* w1   = (const float*)d_in[5];
    const float* w2   = (const float*)d_in[6];
    const float* b2   = (const float*)d_in[7];

    char* p = (char*)d_ws;
    auto alloc = [&](size_t bytes) -> char* {
        char* r = p;
        p += (bytes + 255) & ~(size_t)255;
        return r;
    };
    u16* w0h = (u16*)alloc(N0 * N1 * sizeof(u16));
    u16* w0l = (u16*)alloc(N0 * N1 * sizeof(u16));
    u16* w1h = (u16*)alloc(N0 * N1 * sizeof(u16));
    u16* w1l = (u16*)alloc(N0 * N1 * sizeof(u16));
    u16* dh  = (u16*)alloc((size_t)BATCH * NIN * sizeof(u16));
    u16* dl  = (u16*)alloc((size_t)BATCH * NIN * sizeof(u16));
    float* inp1 = (float*)alloc((size_t)BATCH * N1 * sizeof(float));
    float* s0f[2], *s1f[2];
    u16 *s0h[2], *s0l[2], *s1h[2], *s1l[2];
    for (int i = 0; i < 2; ++i) {
        s0f[i] = (float*)alloc((size_t)BATCH * N0 * sizeof(float));
        s1f[i] = (float*)alloc((size_t)BATCH * N1 * sizeof(float));
        s0h[i] = (u16*)alloc((size_t)BATCH * N0 * sizeof(u16));
        s0l[i] = (u16*)alloc((size_t)BATCH * N0 * sizeof(u16));
        s1h[i] = (u16*)alloc((size_t)BATCH * N1 * sizeof(u16));
        s1l[i] = (u16*)alloc((size_t)BATCH * N1 * sizeof(u16));
    }

    prep_kernel<<<1024, 256, 0, stream>>>(w0, w1, data, s0_0, s1_0,
                                          w0h, w0l, w1h, w1l, dh, dl,
                                          s0f[0], s1f[0], s0h[0], s0l[0], s1h[0], s1l[0]);

    inp1_kernel<<<128, 256, 0, stream>>>(dh, dl, w2, b2, inp1);

    float* out_s0 = (float*)d_out;
    float* out_s1 = (float*)d_out + (size_t)BATCH * N0;

    for (int t = 0; t < TSTEPS; ++t) {
        const int cur = t & 1, nxt = cur ^ 1;
        float* s0o = (t == TSTEPS - 1) ? out_s0 : s0f[nxt];
        float* s1o = (t == TSTEPS - 1) ? out_s1 : s1f[nxt];
        step_kernel<<<256, 256, 0, stream>>>(
            s0f[cur], s1f[cur],
            s0h[cur], s0l[cur], s1h[cur], s1l[cur],
            w0h, w0l, w1h, w1l,
            inp1, b0,
            s0o, s1o,
            s0h[nxt], s0l[nxt], s1h[nxt], s1l[nxt]);
    }
}

// Round 2
// 1735.974 us; speedup vs baseline: 1.4131x; 1.4131x over previous
//
#include <hip/hip_runtime.h>

typedef unsigned short u16;
typedef __attribute__((ext_vector_type(8))) short short8;
typedef __attribute__((ext_vector_type(4))) float f32x4;

#define BATCH 256
#define N0    512
#define N1    2048
#define NIN   4096
#define TSTEPS 60

static __device__ __forceinline__ f32x4 MFMA(short8 a, short8 b, f32x4 c) {
    return __builtin_amdgcn_mfma_f32_16x16x32_bf16(a, b, c, 0, 0, 0);
}

// x = hi + lo (both bf16, truncation split). Residual ~2^-16 relative.
static __device__ __forceinline__ void split1(float x, u16* __restrict__ hp, u16* __restrict__ lp) {
    unsigned bx = __float_as_uint(x);
    *hp = (u16)(bx >> 16);
    float lf = x - __uint_as_float(bx & 0xFFFF0000u);
    *lp = (u16)(__float_as_uint(lf) >> 16);
}

// load 8 contiguous f32 and produce hi/lo bf16x8 fragments (bit-packing)
static __device__ __forceinline__ void split8(const float* __restrict__ p, short8& h, short8& l) {
    const float4 x0 = *(const float4*)p;
    const float4 x1 = *(const float4*)(p + 4);
    float xs[8] = {x0.x, x0.y, x0.z, x0.w, x1.x, x1.y, x1.z, x1.w};
    union { short8 v; unsigned u[4]; } H, L;
    #pragma unroll
    for (int j = 0; j < 4; ++j) {
        unsigned ba = __float_as_uint(xs[2*j]);
        unsigned bb = __float_as_uint(xs[2*j+1]);
        H.u[j] = (ba >> 16) | (bb & 0xFFFF0000u);
        float la = xs[2*j]   - __uint_as_float(ba & 0xFFFF0000u);
        float lb = xs[2*j+1] - __uint_as_float(bb & 0xFFFF0000u);
        L.u[j] = (__float_as_uint(la) >> 16) | (__float_as_uint(lb) & 0xFFFF0000u);
    }
    h = H.v; l = L.v;
}

static __device__ __forceinline__ float clamp01(float v) {
    return fminf(fmaxf(v, 0.0f), 1.0f);
}

// -------- prep: split weights / data / initial states into bf16 hi/lo --------
__global__ __launch_bounds__(256) void prep_kernel(
    const float* __restrict__ w0, const float* __restrict__ w1,
    const float* __restrict__ data,
    const float* __restrict__ s0, const float* __restrict__ s1,
    u16* __restrict__ w0h, u16* __restrict__ w0l,
    u16* __restrict__ w1h, u16* __restrict__ w1l,
    u16* __restrict__ dh,  u16* __restrict__ dl,
    float* __restrict__ s0f, float* __restrict__ s1f,
    u16* __restrict__ s0h, u16* __restrict__ s0l,
    u16* __restrict__ s1h, u16* __restrict__ s1l)
{
    const int tid = blockIdx.x * blockDim.x + threadIdx.x;
    const int nth = gridDim.x * blockDim.x;
    const int NW = N0 * N1;  // 1048576 == BATCH*NIN too
    for (int i = tid; i < NW; i += nth) {
        split1(w0[i],   &w0h[i], &w0l[i]);
        split1(w1[i],   &w1h[i], &w1l[i]);
        split1(data[i], &dh[i],  &dl[i]);
    }
    for (int i = tid; i < BATCH * N0; i += nth) {
        float v = s0[i]; s0f[i] = v; split1(v, &s0h[i], &s0l[i]);
    }
    for (int i = tid; i < BATCH * N1; i += nth) {
        float v = s1[i]; s1f[i] = v; split1(v, &s1h[i], &s1l[i]);
    }
}

// -------- inp1 = data @ w2^T + b2   (M=256, N=2048, K=4096) --------
// 512 WGs, 32x32 tiles (8 x 64); each wave owns one 16x16 quadrant.
__global__ __launch_bounds__(256, 2) void inp1_kernel(
    const u16* __restrict__ dh, const u16* __restrict__ dl,
    const float* __restrict__ w2, const float* __restrict__ b2,
    float* __restrict__ inp1)
{
    const int wave = threadIdx.x >> 6, lane = threadIdx.x & 63;
    const int lrow = lane & 15, lk8 = (lane >> 4) << 3, lr4 = (lane >> 4) << 2;
    const int mbase = (int)(blockIdx.x >> 6) * 32 + (wave >> 1) * 16;
    const int nbase = (int)(blockIdx.x & 63) * 32 + (wave & 1) * 16;

    f32x4 acc0 = {}, acc1 = {}, acc2 = {};
    const size_t arow = (size_t)(mbase + lrow) * NIN;
    const size_t brow = (size_t)(nbase + lrow) * NIN;
    #pragma unroll 4
    for (int k0 = 0; k0 < NIN; k0 += 32) {
        const size_t aoff = arow + k0 + lk8;
        short8 ah = *(const short8*)(dh + aoff);
        short8 al = *(const short8*)(dl + aoff);
        short8 bh, bl;
        split8(w2 + brow + k0 + lk8, bh, bl);
        acc0 = MFMA(ah, bh, acc0);
        acc1 = MFMA(ah, bl, acc1);
        acc2 = MFMA(al, bh, acc2);
    }
    const int col = nbase + lrow;
    const float bias = b2[col];
    #pragma unroll
    for (int r = 0; r < 4; ++r) {
        const int row = mbase + lr4 + r;
        inp1[(size_t)row * N1 + col] = acc0[r] + acc1[r] + acc2[r] + bias;
    }
}

// -------- one Euler step --------
// WGs 0..255  : C1 = s0 @ w1^T rows (K=512), 32x64 tiles, wave = 32x16 -> s1'
// WGs 256..511: C0 = s1 @ w0 rows (K=2048), 16x32 tiles, K split 4-ways
//               across waves + LDS reduction -> s0'
__global__ __launch_bounds__(256, 2) void step_kernel(
    const float* __restrict__ s0f_in, const float* __restrict__ s1f_in,
    const u16* __restrict__ s0h, const u16* __restrict__ s0l,
    const u16* __restrict__ s1h, const u16* __restrict__ s1l,
    const u16* __restrict__ w0h, const u16* __restrict__ w0l,
    const u16* __restrict__ w1h, const u16* __restrict__ w1l,
    const float* __restrict__ inp1, const float* __restrict__ b0,
    float* __restrict__ s0f_out, float* __restrict__ s1f_out,
    u16* __restrict__ s0h_out, u16* __restrict__ s0l_out,
    u16* __restrict__ s1h_out, u16* __restrict__ s1l_out)
{
    const int wg = blockIdx.x;
    const int wave = threadIdx.x >> 6, lane = threadIdx.x & 63;
    const int lrow = lane & 15, lk8 = (lane >> 4) << 3, lr4 = (lane >> 4) << 2;

    if (wg < 256) {
        // ---- C1: s1' tile 32 batches x 64 n1-cols, K = N0 = 512 ----
        const int mbase = (wg >> 5) * 32;             // batch
        const int nbase = (wg & 31) * 64 + wave * 16; // n1 feature (per wave)
        f32x4 acc[2][3] = {};
        const size_t arow0 = (size_t)(mbase + lrow) * N0;
        const size_t arow1 = (size_t)(mbase + 16 + lrow) * N0;
        const size_t browb = (size_t)(nbase + lrow) * N0;
        #pragma unroll 4
        for (int k0 = 0; k0 < N0; k0 += 32) {
            const int ko = k0 + lk8;
            short8 ah0 = *(const short8*)(s0h + arow0 + ko);
            short8 al0 = *(const short8*)(s0l + arow0 + ko);
            short8 ah1 = *(const short8*)(s0h + arow1 + ko);
            short8 al1 = *(const short8*)(s0l + arow1 + ko);
            short8 bh  = *(const short8*)(w1h + browb + ko);
            short8 bl  = *(const short8*)(w1l + browb + ko);
            acc[0][0] = MFMA(ah0, bh, acc[0][0]);
            acc[0][1] = MFMA(ah0, bl, acc[0][1]);
            acc[0][2] = MFMA(al0, bh, acc[0][2]);
            acc[1][0] = MFMA(ah1, bh, acc[1][0]);
            acc[1][1] = MFMA(ah1, bl, acc[1][1]);
            acc[1][2] = MFMA(al1, bh, acc[1][2]);
        }
        const int col = nbase + lrow;
        #pragma unroll
        for (int m = 0; m < 2; ++m) {
            #pragma unroll
            for (int r = 0; r < 4; ++r) {
                const int row = mbase + m * 16 + lr4 + r;
                const size_t idx = (size_t)row * N1 + col;
                const float c = acc[m][0][r] + acc[m][1][r] + acc[m][2][r];
                float v = 0.5f * (s1f_in[idx] + inp1[idx] + c);
                v = clamp01(v);
                s1f_out[idx] = v;
                split1(v, &s1h_out[idx], &s1l_out[idx]);
            }
        }
    } else {
        // ---- C0: s0' tile 16 batches x 32 n0-cols, K = N1 = 2048 split by wave ----
        __shared__ float red[4][16][32];
        const int local = wg - 256;
        const int rowbase = (local >> 4) * 16;  // batch (16 tiles)
        const int colbase = (local & 15) * 32;  // n0 feature (16 tiles)
        const int kbase = wave * 512;           // K chunk per wave
        f32x4 acc[2][3] = {};
        const size_t arow  = (size_t)(rowbase + lrow) * N1;
        const size_t brow0 = (size_t)(colbase + lrow) * N1;
        const size_t brow1 = (size_t)(colbase + 16 + lrow) * N1;
        #pragma unroll 4
        for (int k0 = 0; k0 < 512; k0 += 32) {
            const int ko = kbase + k0 + lk8;
            short8 ah  = *(const short8*)(s1h + arow + ko);
            short8 al  = *(const short8*)(s1l + arow + ko);
            short8 bh0 = *(const short8*)(w0h + brow0 + ko);
            short8 bl0 = *(const short8*)(w0l + brow0 + ko);
            short8 bh1 = *(const short8*)(w0h + brow1 + ko);
            short8 bl1 = *(const short8*)(w0l + brow1 + ko);
            acc[0][0] = MFMA(ah, bh0, acc[0][0]);
            acc[0][1] = MFMA(ah, bl0, acc[0][1]);
            acc[0][2] = MFMA(al, bh0, acc[0][2]);
            acc[1][0] = MFMA(ah, bh1, acc[1][0]);
            acc[1][1] = MFMA(ah, bl1, acc[1][1]);
            acc[1][2] = MFMA(al, bh1, acc[1][2]);
        }
        #pragma unroll
        for (int n = 0; n < 2; ++n) {
            #pragma unroll
            for (int r = 0; r < 4; ++r)
                red[wave][lr4 + r][n * 16 + lrow] =
                    acc[n][0][r] + acc[n][1][r] + acc[n][2][r];
        }
        __syncthreads();
        const int tid = (int)threadIdx.x;
        #pragma unroll
        for (int e = tid; e < 512; e += 256) {
            const int r_ = e >> 5, c_ = e & 31;
            const float sum = red[0][r_][c_] + red[1][r_][c_]
                            + red[2][r_][c_] + red[3][r_][c_];
            const int row = rowbase + r_, col = colbase + c_;
            const size_t idx = (size_t)row * N0 + col;
            float v = 0.5f * (s0f_in[idx] + sum + b0[col]);
            v = clamp01(v);
            s0f_out[idx] = v;
            split1(v, &s0h_out[idx], &s0l_out[idx]);
        }
    }
}

extern "C" void kernel_launch(void* const* d_in, const int* in_sizes, int n_in,
                              void* d_out, int out_size, void* d_ws, size_t ws_size,
                              hipStream_t stream) {
    const float* data = (const float*)d_in[0];
    const float* s0_0 = (const float*)d_in[1];
    const float* s1_0 = (const float*)d_in[2];
    const float* w0   = (const float*)d_in[3];
    const float* b0   = (const float*)d_in[4];
    const float* w1   = (const float*)d_in[5];
    const float* w2   = (const float*)d_in[6];
    const float* b2   = (const float*)d_in[7];

    char* p = (char*)d_ws;
    auto alloc = [&](size_t bytes) -> char* {
        char* r = p;
        p += (bytes + 255) & ~(size_t)255;
        return r;
    };
    u16* w0h = (u16*)alloc(N0 * N1 * sizeof(u16));
    u16* w0l = (u16*)alloc(N0 * N1 * sizeof(u16));
    u16* w1h = (u16*)alloc(N0 * N1 * sizeof(u16));
    u16* w1l = (u16*)alloc(N0 * N1 * sizeof(u16));
    u16* dh  = (u16*)alloc((size_t)BATCH * NIN * sizeof(u16));
    u16* dl  = (u16*)alloc((size_t)BATCH * NIN * sizeof(u16));
    float* inp1 = (float*)alloc((size_t)BATCH * N1 * sizeof(float));
    float* s0f[2], *s1f[2];
    u16 *s0h[2], *s0l[2], *s1h[2], *s1l[2];
    for (int i = 0; i < 2; ++i) {
        s0f[i] = (float*)alloc((size_t)BATCH * N0 * sizeof(float));
        s1f[i] = (float*)alloc((size_t)BATCH * N1 * sizeof(float));
        s0h[i] = (u16*)alloc((size_t)BATCH * N0 * sizeof(u16));
        s0l[i] = (u16*)alloc((size_t)BATCH * N0 * sizeof(u16));
        s1h[i] = (u16*)alloc((size_t)BATCH * N1 * sizeof(u16));
        s1l[i] = (u16*)alloc((size_t)BATCH * N1 * sizeof(u16));
    }

    prep_kernel<<<1024, 256, 0, stream>>>(w0, w1, data, s0_0, s1_0,
                                          w0h, w0l, w1h, w1l, dh, dl,
                                          s0f[0], s1f[0], s0h[0], s0l[0], s1h[0], s1l[0]);

    inp1_kernel<<<512, 256, 0, stream>>>(dh, dl, w2, b2, inp1);

    float* out_s0 = (float*)d_out;
    float* out_s1 = (float*)d_out + (size_t)BATCH * N0;

    for (int t = 0; t < TSTEPS; ++t) {
        const int cur = t & 1, nxt = cur ^ 1;
        float* s0o = (t == TSTEPS - 1) ? out_s0 : s0f[nxt];
        float* s1o = (t == TSTEPS - 1) ? out_s1 : s1f[nxt];
        step_kernel<<<512, 256, 0, stream>>>(
            s0f[cur], s1f[cur],
            s0h[cur], s0l[cur], s1h[cur], s1l[cur],
            w0h, w0l, w1h, w1l,
            inp1, b0,
            s0o, s1o,
            s0h[nxt], s0l[nxt], s1h[nxt], s1l[nxt]);
    }
}